// Round 7
// baseline (291.172 us; speedup 1.0000x reference)
//
#include <hip/hip_runtime.h>
#include <hip/hip_bf16.h>
#include <stdint.h>

// R16: (a) revert k1a to the R14 LDS-transpose featT (R15's register version
// stored 16 B at 256-B stride per instruction -> write-coalescing loss, +32us).
// (b) k4 de-serialized: k1b's iou role now WRITES all 5.76M ious to iouBuf
// [b][n][16] (64-B/thread coalesced) and per-block maxes to mxPart (no
// atomics); k2 block 864 reduces mxPart -> mx; k4 streams iou16 back (4x
// float4) instead of recomputing 32 fdiv chains (R15: k4=65.5us at VGPR 24 =
// compiler-serialized m-loop). iou==mx stays exact: mx is fmax-reduced from
// the SAME stored values. ws grows to ~82.7 MB (iouBuf 23.04 MB).

using bf16x8 = __attribute__((ext_vector_type(8))) __bf16;
using f32x4  = __attribute__((ext_vector_type(4))) float;

// featT2 layout (CHUNK-MAJOR): featT2[chunk 16][img 16][pos 52*52][64 B].
#define FT_CHUNK_STRIDE 2768896   // 16 img * 2704 pos * 64 B
// W2 layout (PACKED+SWIZZLED): [ci-chunk 16][tap 9][cf 3][rec 16][64 B].
#define W2_CHUNK_B 27648

// ---------- helpers ----------
__device__ __forceinline__ unsigned short f2bf(float f) {
  union { float f; unsigned u; } x; x.f = f;
  unsigned r = x.u + 0x7fffu + ((x.u >> 16) & 1u);   // RNE
  return (unsigned short)(r >> 16);
}

__device__ __forceinline__ void gl_lds16(const void* g, void* l) {
  __builtin_amdgcn_global_load_lds(
      (const __attribute__((address_space(1))) void*)g,
      (__attribute__((address_space(3))) void*)l, 16, 0, 0);
}

__device__ __forceinline__ float sl1(float d) {
  float ad = fabsf(d);
  return ad < 1.f ? 0.5f * d * d : ad - 0.5f;
}
__device__ __forceinline__ float softplus_f(float x) {
  return fmaxf(x, 0.f) + log1pf(expf(-fabsf(x)));
}

// strict-fp anchor + IoU (no contraction through __f*_rn).
__device__ __forceinline__ void anchor_strict(int n, float& ax1, float& ay1,
                                              float& ax2, float& ay2) {
  int ii = n / 450;
  int rem = n - ii * 450;
  int jj = rem / 9;
  int a  = rem - jj * 9;
  const float SC[3] = {2.f, 4.f, 6.f};
  const float RA[3] = {0.5f, 1.f, 1.5f};
  float w = __fmul_rn(SC[a % 3], RA[a / 3]);
  float h = SC[a % 3];
  float cx = __fadd_rn((float)ii, 0.5f);
  float cy = __fadd_rn((float)jj, 0.5f);
  float wh = __fmul_rn(w, 0.5f), hh = __fmul_rn(h, 0.5f);
  ax1 = fminf(fmaxf(__fsub_rn(cx, wh), 0.f), 50.f);
  ax2 = fminf(fmaxf(__fadd_rn(cx, wh), 0.f), 50.f);
  ay1 = fminf(fmaxf(__fsub_rn(cy, hh), 0.f), 50.f);
  ay2 = fminf(fmaxf(__fadd_rn(cy, hh), 0.f), 50.f);
}
// s = {gx1,gy1,gx2,gy2,garea} precomputed with the exact reference ops.
__device__ __forceinline__ float iou_pre(float ax1, float ay1, float ax2, float ay2,
                                         float aarea, const float* __restrict__ s) {
  float ix1 = fmaxf(ax1, s[0]), iy1 = fmaxf(ay1, s[1]);
  float ix2 = fminf(ax2, s[2]), iy2 = fminf(ay2, s[3]);
  float inter = __fmul_rn(fmaxf(__fsub_rn(ix2, ix1), 0.f),
                          fmaxf(__fsub_rn(iy2, iy1), 0.f));
  float denom = __fadd_rn(__fsub_rn(__fadd_rn(aarea, s[4]), inter), 1e-8f);
  return __fdiv_rn(inter, denom);
}

// ---------- k1a: featT, LDS transpose (R14 structure, standalone) ----------
// grid 41*4*16 = 2624: tile(41: 40=border) x g(4 ci-groups) x b(16 img)
__global__ __launch_bounds__(256, 6) void k1a(const float* __restrict__ feat,
                                              char* __restrict__ featT2) {
  __shared__ __align__(16) unsigned short sT[64 * 132];  // 16,896 B
  const int bx = blockIdx.x;
  const int tid = threadIdx.x;
  const int tile = bx % 41;
  const int rest = bx / 41;
  const int g    = rest & 3;
  const int b    = rest >> 2;
  if (tile == 40) {                       // border: zero 204 positions' chunks
    uint4 z = {0, 0, 0, 0};
    for (int u = tid; u < 204 * 4; u += 256) {
      int p = u & 255; if (p >= 204) p -= 204;
      int c4 = u / 204;
      int ip, jp;
      if (p < 52)       { ip = 0;       jp = p; }
      else if (p < 104) { ip = 51;      jp = p - 52; }
      else if (p < 154) { ip = p - 103; jp = 0; }
      else              { ip = p - 153; jp = 51; }
      char* dst = featT2 + (size_t)(g * 4 + c4) * FT_CHUNK_STRIDE
                + (size_t)(b * 2704 + ip * 52 + jp) * 64;
      *(uint4*)(dst)      = z;
      *(uint4*)(dst + 16) = z;
      *(uint4*)(dst + 32) = z;
      *(uint4*)(dst + 48) = z;
    }
    return;
  }
  const int pos0 = tile * 64;
  const float* fb = feat + (size_t)b * 1280000 + (size_t)(g * 128) * 2500;
  const int pq = tid & 15;                // pos quad: pos0 + pq*4 .. +3
  const int cq = tid >> 4;                // ci quad group 0..15
  const int p  = pos0 + pq * 4;
  float vv[2][4][4];
  if (p + 3 < 2500) {
#pragma unroll
    for (int it = 0; it < 2; ++it)
#pragma unroll
      for (int q = 0; q < 4; ++q) {
        float4 v = *(const float4*)(fb + (size_t)(it * 64 + cq * 4 + q) * 2500 + p);
        vv[it][q][0] = v.x; vv[it][q][1] = v.y;
        vv[it][q][2] = v.z; vv[it][q][3] = v.w;
      }
  } else {
#pragma unroll
    for (int it = 0; it < 2; ++it)
#pragma unroll
      for (int q = 0; q < 4; ++q)
#pragma unroll
        for (int e = 0; e < 4; ++e)
          vv[it][q][e] = fb[(size_t)(it * 64 + cq * 4 + q) * 2500 + min(p + e, 2499)];
  }
#pragma unroll
  for (int it = 0; it < 2; ++it) {
#pragma unroll
    for (int pp = 0; pp < 4; ++pp) {
      ushort4 pk;
      pk.x = f2bf(vv[it][0][pp]); pk.y = f2bf(vv[it][1][pp]);
      pk.z = f2bf(vv[it][2][pp]); pk.w = f2bf(vv[it][3][pp]);
      *(ushort4*)&sT[(pq * 4 + pp) * 132 + it * 64 + cq * 4] = pk;
    }
  }
  __syncthreads();
  {
    int ch = tid >> 6, pr = tid & 63;     // consecutive threads -> consecutive pos
    int gp = pos0 + pr;
    if (gp < 2500) {
      int i = gp / 50, j = gp - i * 50;
      char* dst = featT2 + (size_t)(g * 4 + ch) * FT_CHUNK_STRIDE
                + (size_t)(b * 2704 + (i + 1) * 52 + (j + 1)) * 64;
      const uint4* src = (const uint4*)&sT[pr * 132 + ch * 32];
      uint4 a0 = src[0], a1 = src[1], a2 = src[2], a3 = src[3];
      *(uint4*)(dst)      = a0;
      *(uint4*)(dst + 16) = a1;
      *(uint4*)(dst + 32) = a2;
      *(uint4*)(dst + 48) = a3;
    }
  }
}

// ---------- k1b: weff1 (0..575) | bias (576..623) | iou+store (624..2031) ----
__global__ __launch_bounds__(256, 4) void k1b(const float* __restrict__ w1,
                                              const float* __restrict__ wc,
                                              const float* __restrict__ wb,
                                              const float* __restrict__ b1,
                                              const float* __restrict__ bc,
                                              const float* __restrict__ bbx,
                                              float* __restrict__ part,
                                              float* __restrict__ bias_eff,
                                              const float* __restrict__ gt_boxes,
                                              float* __restrict__ iouBuf,
                                              float* __restrict__ mxPart,
                                              unsigned* __restrict__ accz) {
  __shared__ __align__(16) float sW[48 * 64];   // weff1; iou role aliases
  const int bxr = blockIdx.x;
  const int tid = threadIdx.x;

  if (bxr < 576) {                   // ---- weff1 role: (cz 8) x (kx 72) ----
    if (bxr == 0 && tid < 8) accz[tid] = 0u;
    int cz = bxr / 72, kx = bxr - cz * 72;
#pragma unroll
    for (int q = 0; q < 12; ++q) {
      int idx = tid + q * 256;
      int co = idx >> 6, cl = idx & 63;
      int c = cz * 64 + cl;
      float v = 0.f;
      if (co < 9) v = wc[co * 512 + c];
      else if (co < 45) v = wb[(co - 9) * 512 + c];
      sW[co * 64 + cl] = v;
    }
    __syncthreads();
    const int kmem = kx * 64 + (tid & 63);
    const int coq  = tid >> 6;
    float acc[12];
#pragma unroll
    for (int j = 0; j < 12; ++j) acc[j] = 0.f;
    const float* w1p = w1 + (size_t)(cz * 64) * 4608 + kmem;
    for (int c4 = 0; c4 < 64; c4 += 4) {
      float f0 = w1p[(size_t)(c4 + 0) * 4608];
      float f1 = w1p[(size_t)(c4 + 1) * 4608];
      float f2 = w1p[(size_t)(c4 + 2) * 4608];
      float f3 = w1p[(size_t)(c4 + 3) * 4608];
#pragma unroll
      for (int j = 0; j < 12; ++j) {
        float4 wv = *(const float4*)&sW[(coq * 12 + j) * 64 + c4];
        acc[j] += wv.x * f0 + wv.y * f1 + wv.z * f2 + wv.w * f3;
      }
    }
    float* dst = part + (size_t)cz * 221184 + kmem;
#pragma unroll
    for (int j = 0; j < 12; ++j) dst[(size_t)(coq * 12 + j) * 4608] = acc[j];
    return;
  }

  if (bxr < 624) {                   // ---- bias-eff role ----
    int co = bxr - 576;
    int l = tid;
    if (l >= 64) return;
    float s = 0.f;
#pragma unroll
    for (int q = 0; q < 8; ++q) {
      int c = q * 64 + l;
      float wv = co < 9 ? wc[co * 512 + c] : (co < 45 ? wb[(co - 9) * 512 + c] : 0.f);
      s += wv * b1[c];
    }
    for (int o = 32; o; o >>= 1) s += __shfl_down(s, o, 64);
    if (l == 0)
      bias_eff[co] = s + (co < 9 ? bc[co] : (co < 45 ? bbx[co - 9] : 0.f));
    return;
  }

  // ---- iou role: block = (b, 256-anchor chunk); writes iouBuf + mxPart ----
  {
    int q = bxr - 624;               // 0..1407
    int b = q / 88, nb = q - b * 88;
    int n = nb * 256 + tid;
    float (*sgg)[5] = (float(*)[5])sW;            // 16*5 floats
    float (*red)[16] = (float(*)[16])(sW + 128);  // 4*16 floats
    if (tid < 16) {
      const float* g = gt_boxes + (b * 16 + tid) * 4;
      float gx1 = __fmul_rn(g[0], 0.0625f), gy1 = __fmul_rn(g[1], 0.0625f);
      float gx2 = __fmul_rn(g[2], 0.0625f), gy2 = __fmul_rn(g[3], 0.0625f);
      sgg[tid][0] = gx1; sgg[tid][1] = gy1; sgg[tid][2] = gx2; sgg[tid][3] = gy2;
      sgg[tid][4] = __fmul_rn(__fsub_rn(gx2, gx1), __fsub_rn(gy2, gy1));
    }
    __syncthreads();
    float lm[16];
#pragma unroll
    for (int m = 0; m < 16; ++m) lm[m] = 0.f;
    if (n < 22500) {
      float ax1, ay1, ax2, ay2;
      anchor_strict(n, ax1, ay1, ax2, ay2);
      float aarea = __fmul_rn(__fsub_rn(ax2, ax1), __fsub_rn(ay2, ay1));
#pragma unroll
      for (int m = 0; m < 16; ++m)
        lm[m] = iou_pre(ax1, ay1, ax2, ay2, aarea, sgg[m]);
      float* dv = iouBuf + (size_t)(b * 22500 + n) * 16;
#pragma unroll
      for (int v4 = 0; v4 < 4; ++v4) {
        float4 pk;
        pk.x = lm[v4 * 4 + 0]; pk.y = lm[v4 * 4 + 1];
        pk.z = lm[v4 * 4 + 2]; pk.w = lm[v4 * 4 + 3];
        *(float4*)(dv + v4 * 4) = pk;
      }
    }
#pragma unroll
    for (int m = 0; m < 16; ++m) {
      float v = lm[m];
      for (int o = 32; o; o >>= 1) v = fmaxf(v, __shfl_down(v, o, 64));
      if ((tid & 63) == 0) red[tid >> 6][m] = v;
    }
    __syncthreads();
    if (tid < 16) {
      float v = fmaxf(fmaxf(red[0][tid], red[1][tid]),
                      fmaxf(red[2][tid], red[3][tid]));
      mxPart[(b * 16 + tid) * 88 + nb] = v;       // plain store, no atomics
    }
  }
}

// ---------- k2: W2 reduce (0..863) | mx reduce (864) ----------
__global__ __launch_bounds__(256) void k2(const float* __restrict__ part,
                                          unsigned short* __restrict__ w2,
                                          const float* __restrict__ mxPart,
                                          unsigned* __restrict__ mx) {
  if (blockIdx.x == 864) {                 // mx[b*16+m] = max over 88 partials
    int t = threadIdx.x;                   // t = b*16+m, 0..255
    const float* mp = mxPart + t * 88;
    float v = 0.f;
    for (int k = 0; k < 88; ++k) v = fmaxf(v, mp[k]);
    mx[t] = __float_as_uint(v);
    return;
  }
  int co = blockIdx.x / 18, kx = blockIdx.x - co * 18;
  int kmem = kx * 256 + threadIdx.x;       // 0..4607
  const float* p = part + (size_t)co * 4608 + kmem;
  float s = 0.f;
#pragma unroll
  for (int cz = 0; cz < 8; ++cz) s += p[(size_t)cz * 221184];
  int ci = kmem / 9, tap = kmem - ci * 9;
  int c = ci >> 5, e = ci & 31;
  int boff = c * W2_CHUNK_B + tap * 3072 + (co >> 4) * 1024 + (co & 15) * 64
           + ((((e >> 3) ^ co) & 3) << 4) + ((e & 7) << 1);
  w2[boff >> 1] = f2bf(s);
}

// ---------- k3: direct conv+head: 4x8 spatial tiles, 2 blocks/CU ----------
__global__ __launch_bounds__(256, 2) void k3(const char* __restrict__ featT2,
                                             const char* __restrict__ w2g,
                                             const float* __restrict__ beff,
                                             float* __restrict__ oh) {
  __shared__ __align__(16) char sF[2][11264];
  __shared__ __align__(16) char sA[2][27648];
  const int tid = threadIdx.x, lane = tid & 63, w = tid >> 6;
  const int bx0 = blockIdx.x;
  const int bx = ((bx0 & 7) << 6) | (bx0 >> 3);
  const int b = bx >> 5, tl = bx & 31, tr = tl >> 3, tc = tl & 7;
  const int i0 = tr * 13 - (tr == 3 ? 1 : 0);
  const int TI = (tr >= 2) ? 12 : 13;
  const int TJ = (tc < 2) ? 7 : 6;
  const int j0 = (tc < 2) ? tc * 7 : 14 + (tc - 2) * 6;
  const int TJ2 = TJ + 2;
  const int mcount = TI * TJ;
  const int pieces = (TI + 2) * TJ2 * 5;

  const char* srcF[3];
#pragma unroll
  for (int k = 0; k < 3; ++k) {
    int s = w * 3 + k;
    int pi = s * 64 + lane;
    if (pi >= pieces) pi = pieces - 1;
    int pos = pi / 5, pc = pi - pos * 5;
    if (pc > 3) pc = 3;
    int hi = pos / TJ2, hj = pos - hi * TJ2;
    srcF[k] = featT2 + (size_t)(b * 2704 + (i0 + hi) * 52 + (j0 + hj)) * 64 + pc * 16;
  }
  int idxB[2];
#pragma unroll
  for (int bf = 0; bf < 2; ++bf) {
    int p = (w * 2 + bf) * 16 + (lane & 15);
    if (p >= mcount) p = mcount - 1;
    int di = p / TJ, dj = p - di * TJ;
    idxB[bf] = (di * TJ2 + dj) * 80 + (lane >> 4) * 16;
  }
  const int aoff = (lane & 15) * 64 + ((((lane >> 4) ^ lane) & 3) << 4);
  int toff[9];
#pragma unroll
  for (int tp = 0; tp < 9; ++tp) toff[tp] = ((tp / 3) * TJ2 + (tp % 3)) * 80;

  f32x4 acc[3][2] = {};

  auto stage = [&](int c, int pb) {
    size_t coff = (size_t)c * FT_CHUNK_STRIDE;
#pragma unroll
    for (int k = 0; k < 3; ++k) {
      int s = w * 3 + k;
      if (s < 11) gl_lds16(srcF[k] + coff, sF[pb] + s * 1024);
    }
#pragma unroll
    for (int k = 0; k < 7; ++k) {
      int s = w + 4 * k;
      if (s < 27)
        gl_lds16(w2g + (size_t)c * W2_CHUNK_B + s * 1024 + lane * 16, sA[pb] + s * 1024);
    }
  };

  stage(0, 0);
  __builtin_amdgcn_s_waitcnt(0);
  __syncthreads();

  for (int c = 0; c < 16; ++c) {
    int pb = c & 1;
    if (c < 15) stage(c + 1, pb ^ 1);
    const char* fA = sA[pb];
    const char* fB = sF[pb];
#pragma unroll
    for (int tp = 0; tp < 9; ++tp) {
      bf16x8 av[3], bv[2];
#pragma unroll
      for (int cf = 0; cf < 3; ++cf)
        av[cf] = *(const bf16x8*)(fA + tp * 3072 + cf * 1024 + aoff);
#pragma unroll
      for (int bf = 0; bf < 2; ++bf)
        bv[bf] = *(const bf16x8*)(fB + idxB[bf] + toff[tp]);
#pragma unroll
      for (int cf = 0; cf < 3; ++cf)
#pragma unroll
        for (int bf = 0; bf < 2; ++bf)
          acc[cf][bf] = __builtin_amdgcn_mfma_f32_16x16x32_bf16(av[cf], bv[bf], acc[cf][bf], 0, 0, 0);
    }
    __builtin_amdgcn_s_waitcnt(0);
    __syncthreads();
  }

  f32x4 bias[3];
#pragma unroll
  for (int cf = 0; cf < 3; ++cf)
    bias[cf] = *(const f32x4*)(beff + cf * 16 + (lane >> 4) * 4);
#pragma unroll
  for (int bf = 0; bf < 2; ++bf) {
    int p = (w * 2 + bf) * 16 + (lane & 15);
    if (p >= mcount) continue;
    int di = p / TJ, dj = p - di * TJ;
    int gm = (b * 50 + i0 + di) * 50 + (j0 + dj);
#pragma unroll
    for (int cf = 0; cf < 3; ++cf) {
      f32x4 v = acc[cf][bf];
#pragma unroll
      for (int r = 0; r < 4; ++r) v[r] += bias[cf][r];
      *(f32x4*)(oh + (size_t)gm * 48 + cf * 16 + (lane >> 4) * 4) = v;
    }
  }
}

// ---------- k4: loss from stored ious + last-block finalize ----------
__global__ __launch_bounds__(256, 2) void k4(const float* __restrict__ gt_boxes,
                                             const unsigned* __restrict__ mxbuf,
                                             const float* __restrict__ iouBuf,
                                             const float* __restrict__ oh,
                                             float* __restrict__ accum,
                                             float* __restrict__ dout) {
  const int tid = threadIdx.x;
  const int b = blockIdx.y;
  __shared__ float sg[16][5];   // gcx,gcy,gw,gh,mxv
  if (tid < 16) {
    const float* g = gt_boxes + (b * 16 + tid) * 4;
    float gx1 = __fmul_rn(g[0], 0.0625f), gy1 = __fmul_rn(g[1], 0.0625f);
    float gx2 = __fmul_rn(g[2], 0.0625f), gy2 = __fmul_rn(g[3], 0.0625f);
    sg[tid][0] = (gx1 + gx2) * 0.5f;
    sg[tid][1] = (gy1 + gy2) * 0.5f;
    sg[tid][2] = fmaxf(gx2 - gx1, 1e-6f);
    sg[tid][3] = fmaxf(gy2 - gy1, 1e-6f);
    sg[tid][4] = __uint_as_float(mxbuf[b * 16 + tid]);
  }
  __syncthreads();

  const int n = blockIdx.x * 256 + tid;
  float s_np = 0.f, s_reg = 0.f, s_pos = 0.f, s_nc = 0.f, s_nl = 0.f;
  if (n < 22500) {
    float ax1, ay1, ax2, ay2;
    anchor_strict(n, ax1, ay1, ax2, ay2);
    float acx = (ax1 + ax2) * 0.5f, acy = (ay1 + ay2) * 0.5f;
    float aw = fmaxf(ax2 - ax1, 1e-6f), ah = fmaxf(ay2 - ay1, 1e-6f);
    int ii = n / 450, rem = n - ii * 450, jj = rem / 9, a = rem - jj * 9;
    const float* row = oh + ((size_t)(b * 2500 + ii * 50 + jj)) * 48;
    float logit = row[a];
    float p0 = row[9 + a * 4], p1 = row[10 + a * 4];
    float p2 = row[11 + a * 4], p3 = row[12 + a * 4];
    // stream the 16 stored ious (coalesced: wave reads 4 KB contiguous)
    const float* iv = iouBuf + (size_t)(b * 22500 + n) * 16;
    float io[16];
#pragma unroll
    for (int v4 = 0; v4 < 4; ++v4) {
      float4 v = *(const float4*)(iv + v4 * 4);
      io[v4 * 4 + 0] = v.x; io[v4 * 4 + 1] = v.y;
      io[v4 * 4 + 2] = v.z; io[v4 * 4 + 3] = v.w;
    }
    int npos = 0;
    bool allneg = true;
#pragma unroll
    for (int m = 0; m < 16; ++m) {
      float iou = io[m];
      float mxv = sg[m][4];
      bool pos = ((iou == mxv) && (mxv > 0.f)) || (iou > 0.7f);
      if (iou >= 0.3f) allneg = false;
      if (pos) {
        ++npos;
        float tx = (sg[m][0] - acx) / aw, ty = (sg[m][1] - acy) / ah;
        float twv = logf(sg[m][2] / aw), thv = logf(sg[m][3] / ah);
        s_reg += sl1(tx - p0) + sl1(ty - p1) + sl1(twv - p2) + sl1(thv - p3);
      }
    }
    s_np = (float)npos;
    s_pos = (float)npos * softplus_f(-logit);
    if (allneg) { s_nc = 1.f; s_nl = softplus_f(logit); }
    float pcx = acx + p0 * aw, pcy = acy + p1 * ah;
    float pw = aw * expf(p2), ph = ah * expf(p3);
    float* o = dout + 1 + ((size_t)b * 22500 + n) * 4;
    o[0] = pcx - pw * 0.5f;
    o[1] = pcy - ph * 0.5f;
    o[2] = pcx + pw * 0.5f;
    o[3] = pcy + ph * 0.5f;
  }
  float vals[5] = {s_np, s_reg, s_pos, s_nc, s_nl};
  __shared__ float red[4][5];
#pragma unroll
  for (int q = 0; q < 5; ++q) {
    float v = vals[q];
    for (int o = 32; o; o >>= 1) v += __shfl_down(v, o, 64);
    if ((tid & 63) == 0) red[tid >> 6][q] = v;
  }
  __syncthreads();
  if (tid < 5) {
    float v = red[0][tid] + red[1][tid] + red[2][tid] + red[3][tid];
    atomicAdd(accum + tid, v);
  }
  __syncthreads();
  if (tid == 0) {
    __threadfence();
    unsigned old = atomicAdd((unsigned*)(accum + 5), 1u);
    if (old == 1407u) {               // 88*16 = 1408 blocks
      float np = fmaxf(atomicAdd(accum + 0, 0.f), 1.f);
      float rg = atomicAdd(accum + 1, 0.f);
      float pp = atomicAdd(accum + 2, 0.f);
      float nn = fmaxf(atomicAdd(accum + 3, 0.f), 1.f);
      float nl = atomicAdd(accum + 4, 0.f);
      dout[0] = 0.5f * (pp / np + nl / nn) + 5.f * (rg / (4.f * np));
    }
  }
}

// ---------- launch ----------
extern "C" void kernel_launch(void* const* d_in, const int* in_sizes, int n_in,
                              void* d_out, int out_size, void* d_ws, size_t ws_size,
                              hipStream_t stream) {
  const float* features = (const float*)d_in[0];
  const float* gt_boxes = (const float*)d_in[1];
  const float* w1    = (const float*)d_in[2];
  const float* b1    = (const float*)d_in[3];
  const float* w_cls = (const float*)d_in[4];
  const float* b_cls = (const float*)d_in[5];
  const float* w_box = (const float*)d_in[6];
  const float* b_box = (const float*)d_in[7];
  float* out = (float*)d_out;
  char* ws = (char*)d_ws;

  // ws layout (total ~82.75 MB)
  char*           featT2 = ws;                                  // 44,302,336 B
  unsigned short* w2     = (unsigned short*)(ws + 44302336);    //    552,960 B
  float*          wpart  = (float*)(ws + 44855296);             //  7,077,888 B
  float*          oh     = (float*)(ws + 51933184);             //  7,680,000 B
  float*          beff   = (float*)(ws + 59613184);             //        192 B
  float*          mxPart = (float*)(ws + 59613376);             //     90,112 B
  unsigned*       mx     = (unsigned*)(ws + 59703488);          //      1,024 B
  float*          accum  = (float*)(ws + 59704512);             //         64 B
  float*          iouBuf = (float*)(ws + 59704576);             // 23,040,000 B

  k1b<<<2032, 256, 0, stream>>>(w1, w_cls, w_box, b1, b_cls, b_box, wpart, beff,
                                gt_boxes, iouBuf, mxPart, (unsigned*)accum);
  k2<<<865, 256, 0, stream>>>(wpart, w2, mxPart, mx);
  k1a<<<2624, 256, 0, stream>>>(features, featT2);
  k3<<<512, 256, 0, stream>>>(featT2, (const char*)w2, beff, oh);
  k4<<<dim3(88, 16), 256, 0, stream>>>(gt_boxes, mx, iouBuf, oh, accum, out);
}